// Round 12
// baseline (525.681 us; speedup 1.0000x reference)
//
#include <hip/hip_runtime.h>
#include <math.h>

#define NND 65536   // total nodes
#define NPER 512    // nodes per graph
#define NGR 128     // graphs (B)
#define DD 128      // feature dim
#define NED 524288  // edges

typedef __attribute__((ext_vector_type(8))) short short8;
typedef __attribute__((ext_vector_type(4))) float f32x4;

__device__ __forceinline__ unsigned short f2b(float f) {
  unsigned u = __float_as_uint(f);
  return (unsigned short)((u + 0x7FFFu + ((u >> 16) & 1u)) >> 16);
}
__device__ __forceinline__ float b2f(unsigned short h) {
  return __uint_as_float(((unsigned)h) << 16);
}

// ---------------- setup: counts=0 + weight prep (fragment order) ----------------

__global__ __launch_bounds__(256) void setup_kernel(
    int* __restrict__ counts,
    const float* __restrict__ wl0, const float* __restrict__ wr0,
    const float* __restrict__ wl1, const float* __restrict__ wr1,
    const float* __restrict__ wl2, const float* __restrict__ wr2,
    unsigned short* __restrict__ Whi, unsigned short* __restrict__ Wlo) {
  const int e = blockIdx.x * 256 + threadIdx.x;  // 384*256 = 98304
  if (e < NND) counts[e] = 0;
  const float* wls[3] = {wl0, wl1, wl2};
  const float* wrs[3] = {wr0, wr1, wr2};
  int l = e >> 15;
  int o = e & 32767;
  int j = o & 7;
  int lane = (o >> 3) & 63;
  int nt = (o >> 9) & 7;
  int kc = o >> 12;
  int li = lane & 15, q = lane >> 4;
  int n = nt * 16 + li;
  int k = kc * 32 + q * 8 + j;
  const float* src = (k < 128) ? wls[l] : wrs[l];
  float v = src[n * DD + (k & 127)];
  unsigned short hi = f2b(v);
  Whi[e] = hi;
  Wlo[e] = f2b(v - b2f(hi));
}

__global__ __launch_bounds__(256) void hist_kernel(const int* __restrict__ ei,
                                                   int* __restrict__ counts) {
  int e = blockIdx.x * 256 + threadIdx.x;
  atomicAdd(&counts[ei[NED + e]], 1);
}

__global__ __launch_bounds__(1024) void scan_kernel(const int* __restrict__ counts,
                                                    int* __restrict__ off,
                                                    int* __restrict__ cursor) {
  __shared__ int part[1024];
  int t = threadIdx.x;
  int base = t * 64;
  int s = 0;
  const int4* c4 = (const int4*)(counts + base);
  for (int i = 0; i < 16; ++i) {
    int4 v = c4[i];
    s += v.x + v.y + v.z + v.w;
  }
  part[t] = s;
  __syncthreads();
  for (int d = 1; d < 1024; d <<= 1) {
    int v = (t >= d) ? part[t - d] : 0;
    __syncthreads();
    part[t] += v;
    __syncthreads();
  }
  int run = (t == 0) ? 0 : part[t - 1];
  for (int i = 0; i < 64; ++i) {
    off[base + i] = run;
    cursor[base + i] = run;
    run += counts[base + i];
  }
  if (t == 1023) off[NND] = NED;
}

__global__ __launch_bounds__(256) void scatter_kernel(const int* __restrict__ ei,
                                                      int* __restrict__ cursor,
                                                      int* __restrict__ ssrc) {
  int e = blockIdx.x * 256 + threadIdx.x;
  int dst = ei[NED + e];
  int pos = atomicAdd(&cursor[dst], 1);
  ssrc[pos] = ei[e];
}

// ---------------- rank helper (exact lax.top_k semantics) ----------------

__device__ __forceinline__ int rank_of(const float* s_sc, const float s, const int n) {
  int r = 0;
  for (int j = 0; j < NPER; j += 4) {
    const float4 sj = *(const float4*)(s_sc + j);
    r += (sj.x > s || (sj.x == s && (j + 0) < n)) ? 1 : 0;
    r += (sj.y > s || (sj.y == s && (j + 1) < n)) ? 1 : 0;
    r += (sj.z > s || (sj.z == s && (j + 2) < n)) ? 1 : 0;
    r += (sj.w > s || (sj.w == s && (j + 3) < n)) ? 1 : 0;
  }
  return r;
}

// ---------------- agg: 4 consecutive dsts per wave -> mean into LDS fragments ----
// Mean element (tile-row rloc, col c) stored at
// Mh[((c>>5)*2 + (rloc>>4))*64 + ((c&31)>>3)*16 + (rloc&15)]*8 + (c&7)
// so phase-B reads ah[m] = Mh[(kc*2+m)*64 + lane] as a linear 16B/lane sweep.

template <int FIRST>
__device__ __forceinline__ void agg_group4(const int gi, const int row0, const int gl0,
                                           const float* __restrict__ x,
                                           const float2* s_tm,
                                           const int* __restrict__ off,
                                           const int* __restrict__ ssrc,
                                           short* Mh, short* Ml, const int lane) {
  const int half = lane >> 5;
  const int l = lane & 31;
  const int d0 = row0 + gi * 4;
  int offv = 0;
  if (lane < 5) offv = off[d0 + lane];
  float deadv = 1.f;
  if (!FIRST && lane < 4) deadv = s_tm[gl0 + gi * 4 + lane].x;
  const int b0 = __shfl(offv, 0);
  const int b1 = __shfl(offv, 1);
  const int b2 = __shfl(offv, 2);
  const int b3 = __shfl(offv, 3);
  const int e3 = __shfl(offv, 4);
  float dds[4] = {1.f, 1.f, 1.f, 1.f};
  if (!FIRST) {
    dds[0] = __shfl(deadv, 0);
    dds[1] = __shfl(deadv, 1);
    dds[2] = __shfl(deadv, 2);
    dds[3] = __shfl(deadv, 3);
  }
  const int begs[4] = {b0, b1, b2, b3};
  const int ends[4] = {b1, b2, b3, e3};

  float4 acc[4];
  int deg[4];
#pragma unroll
  for (int d = 0; d < 4; ++d) {
    acc[d] = make_float4(0.f, 0.f, 0.f, 0.f);
    deg[d] = 0;
  }

  for (int base = b0; base < e3; base += 64) {
    const int nwin = min(64, e3 - base);
    int sv = 0;
    float tv = 0.f;
    int live = 0;
    if (lane < nwin) {
      sv = ssrc[base + lane];
      if (!FIRST) {
        const float2 mt = s_tm[sv & (NPER - 1)];  // srcs are in-graph; LDS lookup
        live = (mt.x != 0.f);
        tv = mt.y;
      }
    }
    unsigned long long bl;
    if (!FIRST)
      bl = __ballot(live);
    else
      bl = (nwin == 64) ? ~0ull : ((1ull << nwin) - 1);

#pragma unroll
    for (int d = 0; d < 4; ++d) {
      if (!FIRST && dds[d] == 0.f) continue;
      const int wlo = max(begs[d], base);
      const int whi = min(ends[d], base + 64);
      if (wlo >= whi) continue;
      const int j0 = wlo - base;
      const int j1 = whi - base;
      const unsigned long long wm =
          (((j1 == 64) ? ~0ull : ((1ull << j1) - 1)) & ~((1ull << j0) - 1));
      deg[d] += (int)__popcll(bl & wm);
      int j = j0 + half;
      for (; j + 6 < j1; j += 8) {  // 4 edges per 32-lane half in flight
        const int s0 = __shfl(sv, j);
        const int s1 = __shfl(sv, j + 2);
        const int s2 = __shfl(sv, j + 4);
        const int s3 = __shfl(sv, j + 6);
        const float4 v0 = *(const float4*)(x + (size_t)s0 * DD + l * 4);
        const float4 v1 = *(const float4*)(x + (size_t)s1 * DD + l * 4);
        const float4 v2 = *(const float4*)(x + (size_t)s2 * DD + l * 4);
        const float4 v3 = *(const float4*)(x + (size_t)s3 * DD + l * 4);
        if (!FIRST) {
          const float t0 = __shfl(tv, j), t1 = __shfl(tv, j + 2);
          const float t2 = __shfl(tv, j + 4), t3 = __shfl(tv, j + 6);
          acc[d].x += v0.x * t0 + v1.x * t1 + v2.x * t2 + v3.x * t3;
          acc[d].y += v0.y * t0 + v1.y * t1 + v2.y * t2 + v3.y * t3;
          acc[d].z += v0.z * t0 + v1.z * t1 + v2.z * t2 + v3.z * t3;
          acc[d].w += v0.w * t0 + v1.w * t1 + v2.w * t2 + v3.w * t3;
        } else {
          acc[d].x += v0.x + v1.x + v2.x + v3.x;
          acc[d].y += v0.y + v1.y + v2.y + v3.y;
          acc[d].z += v0.z + v1.z + v2.z + v3.z;
          acc[d].w += v0.w + v1.w + v2.w + v3.w;
        }
      }
      for (; j < j1; j += 2) {
        const int s = __shfl(sv, j);
        const float4 v = *(const float4*)(x + (size_t)s * DD + l * 4);
        if (!FIRST) {
          const float t = __shfl(tv, j);
          acc[d].x += v.x * t;
          acc[d].y += v.y * t;
          acc[d].z += v.z * t;
          acc[d].w += v.w * t;
        } else {
          acc[d].x += v.x;
          acc[d].y += v.y;
          acc[d].z += v.z;
          acc[d].w += v.w;
        }
      }
    }
  }

#pragma unroll
  for (int d = 0; d < 4; ++d) {
    float4 a = acc[d];
    a.x += __shfl(a.x, lane ^ 32);
    a.y += __shfl(a.y, lane ^ 32);
    a.z += __shfl(a.z, lane ^ 32);
    a.w += __shfl(a.w, lane ^ 32);
    if (lane < 32) {
      const float inv = (!FIRST && dds[d] == 0.f) ? 0.f : (1.f / (float)max(deg[d], 1));
      float4 m;
      m.x = a.x * inv;
      m.y = a.y * inv;
      m.z = a.z * inv;
      m.w = a.w * inv;
      // lane l holds cols 4l..4l+3 of tile-row rloc
      const int rloc = gi * 4 + d;
      const int mm = rloc >> 4;
      const int ri = rloc & 15;
      const int kc2 = l >> 3;
      const int q2 = (l & 7) >> 1;
      const int h4 = l & 1;
      const int idx = ((kc2 * 2 + mm) * 64 + q2 * 16 + ri) * 8 + h4 * 4;
      ushort4 hv, lv;
      hv.x = f2b(m.x); lv.x = f2b(m.x - b2f(hv.x));
      hv.y = f2b(m.y); lv.y = f2b(m.y - b2f(hv.y));
      hv.z = f2b(m.z); lv.z = f2b(m.z - b2f(hv.z));
      hv.w = f2b(m.w); lv.w = f2b(m.w - b2f(hv.w));
      *(ushort4*)(Mh + idx) = hv;
      *(ushort4*)(Ml + idx) = lv;
    }
  }
}

// ---------------- fused layer: pool(prev) + agg + barrier-free MFMA GEMM --------
// L=0: no pool, ungated gather, unscaled Ax.
// L>=1: phase P computes prev-layer top-k (from sraw_prev) -> s_tm (LDS),
//   mtile0 writes tm for layer L+2, per-tile readout partials -> zpart;
//   gather gated/scaled by s_tm; Ax rows scaled by t.
// GBM=32, 2048 blocks; mean lives in LDS fragments -> K-loop has NO barriers.

template <int L>
__global__ __launch_bounds__(256) void layer_kernel(
    const float* __restrict__ x, const float* __restrict__ sprev,
    const float2* __restrict__ tmPrev, const float* __restrict__ pwPrev,
    const int kkPrev, float2* __restrict__ tmOut, float* __restrict__ zpOut,
    const int* __restrict__ off, const int* __restrict__ ssrc,
    const unsigned short* __restrict__ Whi, const unsigned short* __restrict__ Wlo,
    const float* __restrict__ bias, const float* __restrict__ pw,
    float* __restrict__ outp, float* __restrict__ sraw) {
  __shared__ short Mh[4096];  // 8 KB mean fragments (hi)
  __shared__ short Ml[4096];  // 8 KB (lo)
  __shared__ float2 s_tm[NPER];            // 4 KB  sel/tanh of prev pool
  __shared__ alignas(16) float scbuf[1024];  // 4 KB  scores, then readout scratch
  __shared__ float s_sp[4][32];
  __shared__ float s_norm;
  const int tid = threadIdx.x;
  const int wv = tid >> 6;
  const int lane = tid & 63;
  const int q = lane >> 4;
  const int li = lane & 15;
  // 2048 blocks = 8 xcd * 16 graphs * 16 tiles
  const int bid = blockIdx.x;
  const int xcd = bid & 7;
  const int slot = bid >> 3;
  const int graph = xcd * 16 + (slot >> 4);
  const int mtile = slot & 15;
  const int row0 = graph * NPER + mtile * 32;
  const int gl0 = mtile * 32;

  if (L > 0) {
    // ---- phase P: previous layer's top-k pool ----
    if (tid < 64) {
      const float v0 = pwPrev[lane], v1 = pwPrev[lane + 64];
      float p = v0 * v0 + v1 * v1;
#pragma unroll
      for (int o = 32; o > 0; o >>= 1) p += __shfl_down(p, o);
      if (lane == 0) s_norm = 1.f / (sqrtf(p) + 1e-16f);
    }
    __syncthreads();
    const float inv_norm = s_norm;
    const int node0 = graph * NPER + tid;
    const int node1 = node0 + 256;
    float sc0 = sprev[node0] * inv_norm;
    float sc1 = sprev[node1] * inv_norm;
    if (L == 2) {
      if (tmPrev[node0].x == 0.f) sc0 = -INFINITY;
      if (tmPrev[node1].x == 0.f) sc1 = -INFINITY;
    }
    scbuf[tid] = sc0;
    scbuf[tid + 256] = sc1;
    __syncthreads();
    const int r0 = rank_of(scbuf, sc0, tid);
    const int r1 = rank_of(scbuf, sc1, tid + 256);
    const float2 tm0 = (r0 < kkPrev) ? make_float2(1.f, tanhf(sc0)) : make_float2(0.f, 0.f);
    const float2 tm1 = (r1 < kkPrev) ? make_float2(1.f, tanhf(sc1)) : make_float2(0.f, 0.f);
    s_tm[tid] = tm0;
    s_tm[tid + 256] = tm1;
    if (mtile == 0) {
      tmOut[node0] = tm0;
      tmOut[node1] = tm1;
    }
    __syncthreads();

    // ---- per-tile readout partials of x (= h_L) scaled by t ----
    {
      float4* red4 = (float4*)scbuf;
      const int c = tid & 31;
      const int rg = tid >> 5;
      float4 rmax = make_float4(-INFINITY, -INFINITY, -INFINITY, -INFINITY);
      float4 rsum = make_float4(0.f, 0.f, 0.f, 0.f);
#pragma unroll
      for (int i = 0; i < 4; ++i) {
        const int rloc = rg + 8 * i;
        const float2 mt = s_tm[gl0 + rloc];
        float4 v = *(const float4*)(x + (size_t)(row0 + rloc) * DD + c * 4);
        v.x *= mt.y; v.y *= mt.y; v.z *= mt.y; v.w *= mt.y;
        rsum.x += v.x; rsum.y += v.y; rsum.z += v.z; rsum.w += v.w;
        if (mt.x != 0.f) {
          rmax.x = fmaxf(rmax.x, v.x);
          rmax.y = fmaxf(rmax.y, v.y);
          rmax.z = fmaxf(rmax.z, v.z);
          rmax.w = fmaxf(rmax.w, v.w);
        }
      }
      red4[rg * 32 + c] = rmax;
      __syncthreads();
      float4 zm = make_float4(0.f, 0.f, 0.f, 0.f);
      if (tid < 32) {
        zm = red4[tid];
#pragma unroll
        for (int rr = 1; rr < 8; ++rr) {
          const float4 a = red4[rr * 32 + tid];
          zm.x = fmaxf(zm.x, a.x); zm.y = fmaxf(zm.y, a.y);
          zm.z = fmaxf(zm.z, a.z); zm.w = fmaxf(zm.w, a.w);
        }
      }
      __syncthreads();
      red4[rg * 32 + c] = rsum;
      __syncthreads();
      if (tid < 32) {
        float4 zs = red4[tid];
#pragma unroll
        for (int rr = 1; rr < 8; ++rr) {
          const float4 a = red4[rr * 32 + tid];
          zs.x += a.x; zs.y += a.y; zs.z += a.z; zs.w += a.w;
        }
        float* zp = zpOut + (size_t)(graph * 16 + mtile) * 256;
        *(float4*)(zp + tid * 4) = zm;
        *(float4*)(zp + 128 + tid * 4) = zs;
      }
    }
  }

  // ---- phase A: aggregate this tile's 32 rows into LDS fragments ----
#pragma unroll
  for (int s = 0; s < 2; ++s)
    agg_group4<(L == 0)>(s * 4 + wv, row0, gl0, x, s_tm, off, ssrc, Mh, Ml, lane);
  __syncthreads();

  // ---- phase B: barrier-free MFMA bf16x3 GEMM (32 rows) ----
  float tsm[2] = {1.f, 1.f};
  if (L > 0) {
    tsm[0] = s_tm[gl0 + li].y;
    tsm[1] = s_tm[gl0 + 16 + li].y;
  }
  f32x4 acc[2][2];
#pragma unroll
  for (int m = 0; m < 2; ++m)
#pragma unroll
    for (int n = 0; n < 2; ++n) acc[m][n] = (f32x4){0.f, 0.f, 0.f, 0.f};

#pragma unroll
  for (int kc = 0; kc < 8; ++kc) {
    short8 ah[2], al[2], bh[2], bl[2];
    if (kc < 4) {
#pragma unroll
      for (int m = 0; m < 2; ++m) {
        const int idx = ((kc * 2 + m) * 64 + lane) * 8;
        ah[m] = *(const short8*)(Mh + idx);
        al[m] = *(const short8*)(Ml + idx);
      }
    } else {
#pragma unroll
      for (int m = 0; m < 2; ++m) {
        const float* xr = x + (size_t)(row0 + m * 16 + li) * DD + (kc - 4) * 32 + q * 8;
        float4 f0 = *(const float4*)xr;
        float4 f1 = *(const float4*)(xr + 4);
        if (L > 0) {
          const float t = tsm[m];
          f0.x *= t; f0.y *= t; f0.z *= t; f0.w *= t;
          f1.x *= t; f1.y *= t; f1.z *= t; f1.w *= t;
        }
        const float fv[8] = {f0.x, f0.y, f0.z, f0.w, f1.x, f1.y, f1.z, f1.w};
        short8 hh, ll;
#pragma unroll
        for (int e = 0; e < 8; ++e) {
          const unsigned short h = f2b(fv[e]);
          hh[e] = (short)h;
          ll[e] = (short)f2b(fv[e] - b2f(h));
        }
        ah[m] = hh;
        al[m] = ll;
      }
    }
#pragma unroll
    for (int n = 0; n < 2; ++n) {
      const int ga = ((kc * 8 + wv * 2 + n) * 64 + lane) * 8;
      bh[n] = *(const short8*)(Whi + ga);
      bl[n] = *(const short8*)(Wlo + ga);
    }
#pragma unroll
    for (int m = 0; m < 2; ++m)
#pragma unroll
      for (int n = 0; n < 2; ++n) {
        acc[m][n] = __builtin_amdgcn_mfma_f32_16x16x32_bf16(ah[m], bh[n], acc[m][n], 0, 0, 0);
        acc[m][n] = __builtin_amdgcn_mfma_f32_16x16x32_bf16(ah[m], bl[n], acc[m][n], 0, 0, 0);
        acc[m][n] = __builtin_amdgcn_mfma_f32_16x16x32_bf16(al[m], bh[n], acc[m][n], 0, 0, 0);
      }
  }

  // ---- epilogue: bias+relu, store h, fused score -> sraw ----
  const int c0 = wv * 32 + li;
  const int c1 = c0 + 16;
  const float b0 = bias[c0], b1 = bias[c1];
  const float p0 = pw[c0], p1 = pw[c1];
  float sp[8];
#pragma unroll
  for (int m = 0; m < 2; ++m) {
#pragma unroll
    for (int i = 0; i < 4; ++i) {
      const int r = row0 + m * 16 + q * 4 + i;
      const float v0 = fmaxf(acc[m][0][i] + b0, 0.f);
      const float v1 = fmaxf(acc[m][1][i] + b1, 0.f);
      outp[(size_t)r * DD + c0] = v0;
      outp[(size_t)r * DD + c1] = v1;
      sp[m * 4 + i] = v0 * p0 + v1 * p1;
    }
  }
#pragma unroll
  for (int e = 0; e < 8; ++e) {
    sp[e] += __shfl_xor(sp[e], 1);
    sp[e] += __shfl_xor(sp[e], 2);
    sp[e] += __shfl_xor(sp[e], 4);
    sp[e] += __shfl_xor(sp[e], 8);
  }
  if (li == 0) {
#pragma unroll
    for (int e = 0; e < 8; ++e) s_sp[wv][(e >> 2) * 16 + q * 4 + (e & 3)] = sp[e];
  }
  __syncthreads();
  if (tid < 32)
    sraw[row0 + tid] = s_sp[0][tid] + s_sp[1][tid] + s_sp[2][tid] + s_sp[3][tid];
}

// ---------------- MLP head: pool-3 + readout-3 + zpart reduce + MLP ----------------

__global__ __launch_bounds__(256) void mlp_kernel(
    const float* __restrict__ h3, const float* __restrict__ s2buf,
    const float2* __restrict__ tm2, const float* __restrict__ pw2,
    const float* __restrict__ zpart,
    const float* __restrict__ w1, const float* __restrict__ b1,
    const float* __restrict__ w2, const float* __restrict__ b2,
    const float* __restrict__ w3, const float* __restrict__ b3,
    float* __restrict__ out) {
  __shared__ float2 s_tm[NPER];
  __shared__ alignas(16) float scbuf[1024];
  __shared__ float z3m[128], z3s[128];
  __shared__ float z[256], sh1[128], sh2[64];
  __shared__ float s_norm;
  const int g = blockIdx.x;
  const int tid = threadIdx.x;
  const int lane = tid & 63;

  if (tid < 64) {
    const float v0 = pw2[lane], v1 = pw2[lane + 64];
    float p = v0 * v0 + v1 * v1;
#pragma unroll
    for (int o = 32; o > 0; o >>= 1) p += __shfl_down(p, o);
    if (lane == 0) s_norm = 1.f / (sqrtf(p) + 1e-16f);
  }
  __syncthreads();
  const float inv_norm = s_norm;
  const int node0 = g * NPER + tid;
  const int node1 = node0 + 256;
  float sc0 = (tm2[node0].x != 0.f) ? s2buf[node0] * inv_norm : -INFINITY;
  float sc1 = (tm2[node1].x != 0.f) ? s2buf[node1] * inv_norm : -INFINITY;
  scbuf[tid] = sc0;
  scbuf[tid + 256] = sc1;
  __syncthreads();
  const int r0 = rank_of(scbuf, sc0, tid);
  const int r1 = rank_of(scbuf, sc1, tid + 256);
  s_tm[tid] = (r0 < 263) ? make_float2(1.f, tanhf(sc0)) : make_float2(0.f, 0.f);
  s_tm[tid + 256] = (r1 < 263) ? make_float2(1.f, tanhf(sc1)) : make_float2(0.f, 0.f);
  __syncthreads();

  // readout of h3 (whole graph)
  {
    float4* red4 = (float4*)scbuf;
    const int c = tid & 31;
    const int rg = tid >> 5;
    float4 rmax = make_float4(-INFINITY, -INFINITY, -INFINITY, -INFINITY);
    float4 rsum = make_float4(0.f, 0.f, 0.f, 0.f);
    for (int i = 0; i < 64; ++i) {
      const int rloc = rg + 8 * i;
      const float2 mt = s_tm[rloc];
      float4 v = *(const float4*)(h3 + (size_t)(g * NPER + rloc) * DD + c * 4);
      v.x *= mt.y; v.y *= mt.y; v.z *= mt.y; v.w *= mt.y;
      rsum.x += v.x; rsum.y += v.y; rsum.z += v.z; rsum.w += v.w;
      if (mt.x != 0.f) {
        rmax.x = fmaxf(rmax.x, v.x);
        rmax.y = fmaxf(rmax.y, v.y);
        rmax.z = fmaxf(rmax.z, v.z);
        rmax.w = fmaxf(rmax.w, v.w);
      }
    }
    red4[rg * 32 + c] = rmax;
    __syncthreads();
    float4 zm = make_float4(0.f, 0.f, 0.f, 0.f);
    if (tid < 32) {
      zm = red4[tid];
#pragma unroll
      for (int rr = 1; rr < 8; ++rr) {
        const float4 a = red4[rr * 32 + tid];
        zm.x = fmaxf(zm.x, a.x); zm.y = fmaxf(zm.y, a.y);
        zm.z = fmaxf(zm.z, a.z); zm.w = fmaxf(zm.w, a.w);
      }
    }
    __syncthreads();
    red4[rg * 32 + c] = rsum;
    __syncthreads();
    if (tid < 32) {
      float4 zs = red4[tid];
#pragma unroll
      for (int rr = 1; rr < 8; ++rr) {
        const float4 a = red4[rr * 32 + tid];
        zs.x += a.x; zs.y += a.y; zs.z += a.z; zs.w += a.w;
      }
      *(float4*)(z3m + tid * 4) = zm;
      *(float4*)(z3s + tid * 4) = zs;
    }
  }
  __syncthreads();

  if (tid < 128) {
    float m0 = -INFINITY, s0 = 0.f, m1 = -INFINITY, s1 = 0.f;
    for (int t = 0; t < 16; ++t) {
      const float* zp0 = zpart + (size_t)(g * 16 + t) * 256;
      const float* zp1 = zpart + (size_t)2048 * 256 + (size_t)(g * 16 + t) * 256;
      m0 = fmaxf(m0, zp0[tid]);
      s0 += zp0[128 + tid];
      m1 = fmaxf(m1, zp1[tid]);
      s1 += zp1[128 + tid];
    }
    z[tid] = m0 + m1 + z3m[tid];
    z[128 + tid] = s0 * (1.f / 410.f) + s1 * (1.f / 328.f) + z3s[tid] * (1.f / 263.f);
  }
  __syncthreads();
  if (tid < 128) {
    float a = b1[tid];
    for (int k = 0; k < 256; ++k) a = fmaf(z[k], w1[tid * 256 + k], a);
    sh1[tid] = fmaxf(a, 0.f);
  }
  __syncthreads();
  if (tid < 64) {
    float a2 = b2[tid];
    for (int k = 0; k < 128; ++k) a2 = fmaf(sh1[k], w2[tid * 128 + k], a2);
    sh2[tid] = fmaxf(a2, 0.f);
  }
  __syncthreads();
  if (tid == 0) {
    float a3 = b3[0];
    for (int k = 0; k < 64; ++k) a3 = fmaf(sh2[k], w3[k], a3);
    out[g] = 1.f / (1.f + expf(-a3));
  }
}

// ---------------- launch ----------------

extern "C" void kernel_launch(void* const* d_in, const int* in_sizes, int n_in,
                              void* d_out, int out_size, void* d_ws, size_t ws_size,
                              hipStream_t stream) {
  (void)in_sizes; (void)n_in; (void)out_size; (void)ws_size;
  const float* x_in = (const float*)d_in[0];
  const int* ei = (const int*)d_in[1];
  const float* wl[3] = {(const float*)d_in[2], (const float*)d_in[6], (const float*)d_in[10]};
  const float* cbl[3] = {(const float*)d_in[3], (const float*)d_in[7], (const float*)d_in[11]};
  const float* wr[3] = {(const float*)d_in[4], (const float*)d_in[8], (const float*)d_in[12]};
  const float* pw[3] = {(const float*)d_in[5], (const float*)d_in[9], (const float*)d_in[13]};
  const float* l1w = (const float*)d_in[14];
  const float* l1b = (const float*)d_in[15];
  const float* l2w = (const float*)d_in[16];
  const float* l2b = (const float*)d_in[17];
  const float* l3w = (const float*)d_in[18];
  const float* l3b = (const float*)d_in[19];
  float* out = (float*)d_out;

  char* w = (char*)d_ws;
  int* counts = (int*)(w + 0 * (1 << 20));                 // 256 KB, dead after scan
  int* off = (int*)(w + 1 * (1 << 20));                    // 256 KB + 4
  int* cursor = (int*)(w + 2 * (1 << 20));                 // 256 KB, dead after scatter
  int* ssrc = (int*)(w + 3 * (1 << 20));                   // 2 MB
  unsigned short* Whi = (unsigned short*)(w + 5 * (1 << 20) + (1 << 18));      // 192 KB
  unsigned short* Wlo = (unsigned short*)(w + 5 * (1 << 20) + (1 << 19));      // 192 KB
  float* s0 = (float*)(w + 6 * (1 << 20));                 // 256 KB
  float* s1 = (float*)(w + 6 * (1 << 20) + (1 << 18));     // 256 KB
  float* s2 = (float*)(w + 6 * (1 << 20) + (1 << 19));     // 256 KB
  float2* tmA = (float2*)(w + 7 * (1 << 20));              // 512 KB
  float2* tmB = (float2*)(w + 7 * (1 << 20) + (1 << 19));  // 512 KB
  float* zpart = (float*)(w + 8 * (1 << 20));              // 4 MB (2 layers x 2 MB)
  float* hA = (float*)(w + (size_t)16 * (1 << 20));        // 32 MB
  float* hB = (float*)(w + (size_t)48 * (1 << 20));        // 32 MB (total 80 MB)

  setup_kernel<<<384, 256, 0, stream>>>(counts, wl[0], wr[0], wl[1], wr[1], wl[2], wr[2],
                                        Whi, Wlo);
  hist_kernel<<<NED / 256, 256, 0, stream>>>(ei, counts);
  scan_kernel<<<1, 1024, 0, stream>>>(counts, off, cursor);
  scatter_kernel<<<NED / 256, 256, 0, stream>>>(ei, cursor, ssrc);

  // layer 1: x -> hA, scores s0
  layer_kernel<0><<<2048, 256, 0, stream>>>(x_in, nullptr, nullptr, nullptr, 0, nullptr,
                                            nullptr, off, ssrc, Whi, Wlo, cbl[0], pw[0],
                                            hA, s0);
  // layer 2: pool0 (s0, k=410) folded; hA -> hB, scores s1; writes tmA, zpart[0]
  layer_kernel<1><<<2048, 256, 0, stream>>>(hA, s0, nullptr, pw[0], 410, tmA, zpart, off,
                                            ssrc, Whi + 32768, Wlo + 32768, cbl[1], pw[1],
                                            hB, s1);
  // layer 3: pool1 (s1, k=328, gated tmA); hB -> hA, scores s2; writes tmB, zpart[1]
  layer_kernel<2><<<2048, 256, 0, stream>>>(hB, s1, tmA, pw[1], 328, tmB,
                                            zpart + (size_t)2048 * 256, off, ssrc,
                                            Whi + 65536, Wlo + 65536, cbl[2], pw[2], hA, s2);
  // head: pool2 (s2, k=263, gated tmB) + readout3 + MLP
  mlp_kernel<<<NGR, 256, 0, stream>>>(hA, s2, tmB, pw[2], zpart, l1w, l1b, l2w, l2b, l3w,
                                      l3b, out);
}

// Round 13
// 424.053 us; speedup vs baseline: 1.2397x; 1.2397x over previous
//
#include <hip/hip_runtime.h>
#include <math.h>

#define NND 65536   // total nodes
#define NPER 512    // nodes per graph
#define NGR 128     // graphs (B)
#define DD 128      // feature dim
#define NED 524288  // edges

typedef __attribute__((ext_vector_type(8))) short short8;
typedef __attribute__((ext_vector_type(4))) float f32x4;

__device__ __forceinline__ unsigned short f2b(float f) {
  unsigned u = __float_as_uint(f);
  return (unsigned short)((u + 0x7FFFu + ((u >> 16) & 1u)) >> 16);
}
__device__ __forceinline__ float b2f(unsigned short h) {
  return __uint_as_float(((unsigned)h) << 16);
}

// ---------------- setup: counts=0, tm={1,1}, weight prep (fragment order) -------

__global__ __launch_bounds__(256) void setup_kernel(
    int* __restrict__ counts, float2* __restrict__ tm,
    const float* __restrict__ wl0, const float* __restrict__ wr0,
    const float* __restrict__ wl1, const float* __restrict__ wr1,
    const float* __restrict__ wl2, const float* __restrict__ wr2,
    unsigned short* __restrict__ Whi, unsigned short* __restrict__ Wlo) {
  const int e = blockIdx.x * 256 + threadIdx.x;  // 384*256 = 98304
  if (e < NND) {
    counts[e] = 0;
    tm[e] = make_float2(1.f, 1.f);  // layer-0 pool gate: all selected
  }
  const float* wls[3] = {wl0, wl1, wl2};
  const float* wrs[3] = {wr0, wr1, wr2};
  int l = e >> 15;
  int o = e & 32767;
  int j = o & 7;
  int lane = (o >> 3) & 63;
  int nt = (o >> 9) & 7;
  int kc = o >> 12;
  int li = lane & 15, q = lane >> 4;
  int n = nt * 16 + li;
  int k = kc * 32 + q * 8 + j;
  const float* src = (k < 128) ? wls[l] : wrs[l];
  float v = src[n * DD + (k & 127)];
  unsigned short hi = f2b(v);
  Whi[e] = hi;
  Wlo[e] = f2b(v - b2f(hi));
}

__global__ __launch_bounds__(256) void hist_kernel(const int* __restrict__ ei,
                                                   int* __restrict__ counts) {
  int e = blockIdx.x * 256 + threadIdx.x;
  atomicAdd(&counts[ei[NED + e]], 1);
}

__global__ __launch_bounds__(1024) void scan_kernel(const int* __restrict__ counts,
                                                    int* __restrict__ off,
                                                    int* __restrict__ cursor) {
  __shared__ int part[1024];
  int t = threadIdx.x;
  int base = t * 64;
  int s = 0;
  const int4* c4 = (const int4*)(counts + base);
  for (int i = 0; i < 16; ++i) {
    int4 v = c4[i];
    s += v.x + v.y + v.z + v.w;
  }
  part[t] = s;
  __syncthreads();
  for (int d = 1; d < 1024; d <<= 1) {
    int v = (t >= d) ? part[t - d] : 0;
    __syncthreads();
    part[t] += v;
    __syncthreads();
  }
  int run = (t == 0) ? 0 : part[t - 1];
  for (int i = 0; i < 64; ++i) {
    off[base + i] = run;
    cursor[base + i] = run;
    run += counts[base + i];
  }
  if (t == 1023) off[NND] = NED;
}

__global__ __launch_bounds__(256) void scatter_kernel(const int* __restrict__ ei,
                                                      int* __restrict__ cursor,
                                                      int* __restrict__ ssrc) {
  int e = blockIdx.x * 256 + threadIdx.x;
  int dst = ei[NED + e];
  int pos = atomicAdd(&cursor[dst], 1);
  ssrc[pos] = ei[e];
}

// ---------------- mean aggregation: 4 dsts/wave, shared prologue (R8) ----------
// ONE coalesced 64-edge window (ssrc + tm gather) serves 4 consecutive dsts.
// Output bf16 hi/lo (mhi/mlo) so gemm's mean staging is a pure copy.

template <int CM>
__global__ __launch_bounds__(256) void agg_kernel_t(const float* __restrict__ x,
                                                    const float2* __restrict__ tm,
                                                    const int* __restrict__ off,
                                                    const int* __restrict__ ssrc,
                                                    unsigned short* __restrict__ mhi,
                                                    unsigned short* __restrict__ mlo) {
  const int wave = threadIdx.x >> 6;
  const int lane = threadIdx.x & 63;
  const int half = lane >> 5;
  const int l = lane & 31;
  // 4096 blocks = 8 xcd * 16 graphs * 32 slots; 16 dsts/block, 4/wave
  const int bid = blockIdx.x;
  const int xcd = bid & 7;
  const int slot = bid >> 3;
  const int graph = xcd * 16 + (slot >> 5);
  const int within = slot & 31;
  const int d0 = graph * NPER + within * 16 + wave * 4;

  int offv = 0;
  if (lane < 5) offv = off[d0 + lane];
  float deadv = 1.f;
  if (CM && lane < 4) deadv = tm[d0 + lane].x;
  const int b0 = __shfl(offv, 0);
  const int b1 = __shfl(offv, 1);
  const int b2 = __shfl(offv, 2);
  const int b3 = __shfl(offv, 3);
  const int e3 = __shfl(offv, 4);
  float dd[4];
  if (CM) {
    dd[0] = __shfl(deadv, 0);
    dd[1] = __shfl(deadv, 1);
    dd[2] = __shfl(deadv, 2);
    dd[3] = __shfl(deadv, 3);
  }
  const int begs[4] = {b0, b1, b2, b3};
  const int ends[4] = {b1, b2, b3, e3};

  float4 acc[4];
  int deg[4];
#pragma unroll
  for (int d = 0; d < 4; ++d) {
    acc[d] = make_float4(0.f, 0.f, 0.f, 0.f);
    deg[d] = 0;
  }

  for (int base = b0; base < e3; base += 64) {
    const int nwin = min(64, e3 - base);
    int sv = 0;
    float tv = 0.f;
    int live = 0;
    if (lane < nwin) {
      sv = ssrc[base + lane];
      if (CM) {
        const float2 mt = tm[sv];
        live = (mt.x != 0.f);
        tv = mt.y;
      }
    }
    unsigned long long bl;
    if (CM)
      bl = __ballot(live);
    else
      bl = (nwin == 64) ? ~0ull : ((1ull << nwin) - 1);

#pragma unroll
    for (int d = 0; d < 4; ++d) {
      if (CM && dd[d] == 0.f) continue;
      const int lo = max(begs[d], base);
      const int hi = min(ends[d], base + 64);
      if (lo >= hi) continue;
      const int j0 = lo - base;
      const int j1 = hi - base;
      const unsigned long long wm =
          (((j1 == 64) ? ~0ull : ((1ull << j1) - 1)) & ~((1ull << j0) - 1));
      deg[d] += (int)__popcll(bl & wm);
      int j = j0 + half;
      for (; j + 6 < j1; j += 8) {  // 4 edges per 32-lane half in flight
        const int s0 = __shfl(sv, j);
        const int s1 = __shfl(sv, j + 2);
        const int s2 = __shfl(sv, j + 4);
        const int s3 = __shfl(sv, j + 6);
        const float4 v0 = *(const float4*)(x + (size_t)s0 * DD + l * 4);
        const float4 v1 = *(const float4*)(x + (size_t)s1 * DD + l * 4);
        const float4 v2 = *(const float4*)(x + (size_t)s2 * DD + l * 4);
        const float4 v3 = *(const float4*)(x + (size_t)s3 * DD + l * 4);
        if (CM) {
          const float t0 = __shfl(tv, j), t1 = __shfl(tv, j + 2);
          const float t2 = __shfl(tv, j + 4), t3 = __shfl(tv, j + 6);
          acc[d].x += v0.x * t0 + v1.x * t1 + v2.x * t2 + v3.x * t3;
          acc[d].y += v0.y * t0 + v1.y * t1 + v2.y * t2 + v3.y * t3;
          acc[d].z += v0.z * t0 + v1.z * t1 + v2.z * t2 + v3.z * t3;
          acc[d].w += v0.w * t0 + v1.w * t1 + v2.w * t2 + v3.w * t3;
        } else {
          acc[d].x += v0.x + v1.x + v2.x + v3.x;
          acc[d].y += v0.y + v1.y + v2.y + v3.y;
          acc[d].z += v0.z + v1.z + v2.z + v3.z;
          acc[d].w += v0.w + v1.w + v2.w + v3.w;
        }
      }
      for (; j < j1; j += 2) {
        const int s = __shfl(sv, j);
        const float4 v = *(const float4*)(x + (size_t)s * DD + l * 4);
        if (CM) {
          const float t = __shfl(tv, j);
          acc[d].x += v.x * t;
          acc[d].y += v.y * t;
          acc[d].z += v.z * t;
          acc[d].w += v.w * t;
        } else {
          acc[d].x += v.x;
          acc[d].y += v.y;
          acc[d].z += v.z;
          acc[d].w += v.w;
        }
      }
    }
  }

#pragma unroll
  for (int d = 0; d < 4; ++d) {
    float4 a = acc[d];
    a.x += __shfl(a.x, lane ^ 32);
    a.y += __shfl(a.y, lane ^ 32);
    a.z += __shfl(a.z, lane ^ 32);
    a.w += __shfl(a.w, lane ^ 32);
    if (lane < 32) {
      const float inv = 1.f / (float)max(deg[d], 1);
      float4 m;
      m.x = a.x * inv;
      m.y = a.y * inv;
      m.z = a.z * inv;
      m.w = a.w * inv;
      ushort4 hv, lv;
      hv.x = f2b(m.x); lv.x = f2b(m.x - b2f(hv.x));
      hv.y = f2b(m.y); lv.y = f2b(m.y - b2f(hv.y));
      hv.z = f2b(m.z); lv.z = f2b(m.z - b2f(hv.z));
      hv.w = f2b(m.w); lv.w = f2b(m.w - b2f(hv.w));
      const size_t ad = (size_t)(d0 + d) * DD + l * 4;
      *(ushort4*)(mhi + ad) = hv;
      *(ushort4*)(mlo + ad) = lv;
    }
  }
}

// ---------------- MFMA bf16x3 GEMM + score epilogue (R8) ----------------

#define GBM 64

template <int SCALE>
__global__ __launch_bounds__(256) void gemm_kernel_t(
    const unsigned short* __restrict__ Amh, const unsigned short* __restrict__ Aml,
    const float* __restrict__ Ax, const float2* __restrict__ tmp,
    const unsigned short* __restrict__ Whi, const unsigned short* __restrict__ Wlo,
    const float* __restrict__ bias, const float* __restrict__ pw,
    float* __restrict__ outp, float* __restrict__ sraw) {
  __shared__ short Ah[2048];  // [m][lane][8]
  __shared__ short Al[2048];
  __shared__ float s_sp[4][GBM];
  const int tid = threadIdx.x;
  const int wv = tid >> 6;
  const int lane = tid & 63;
  const int q = lane >> 4;
  const int li = lane & 15;
  const int row0 = blockIdx.x * GBM;

  int sdst[2];
#pragma unroll
  for (int i = 0; i < 2; ++i) {
    const int id = tid + i * 256;
    const int r = id >> 3;
    const int kb = (id & 7) << 2;
    sdst[i] = ((r >> 4) * 64 + (kb >> 3) * 16 + (r & 15)) * 8 + (kb & 7);
  }

  f32x4 acc[4][2];
#pragma unroll
  for (int m = 0; m < 4; ++m)
#pragma unroll
    for (int n = 0; n < 2; ++n) acc[m][n] = (f32x4){0.f, 0.f, 0.f, 0.f};

  float4 pa[2];
  ushort4 pmh[2], pml[2];
  short8 pbh[2], pbl[2];

#define LOADA(KC)                                                                      \
  {                                                                                    \
    if ((KC) < 4) {                                                                    \
      const int cb = (KC)*32;                                                          \
      _Pragma("unroll") for (int i = 0; i < 2; ++i) {                                  \
        const int id = tid + i * 256;                                                  \
        const size_t ga = (size_t)(row0 + (id >> 3)) * DD + cb + ((id & 7) << 2);      \
        pmh[i] = *(const ushort4*)(Amh + ga);                                          \
        pml[i] = *(const ushort4*)(Aml + ga);                                          \
      }                                                                                \
    } else {                                                                           \
      const int cb = ((KC)&3) * 32;                                                    \
      _Pragma("unroll") for (int i = 0; i < 2; ++i) {                                  \
        const int id = tid + i * 256;                                                  \
        pa[i] = *(const float4*)(Ax + (size_t)(row0 + (id >> 3)) * DD + cb + ((id & 7) << 2)); \
        if (SCALE) {                                                                   \
          const float tt = tmp[row0 + (id >> 3)].y;                                    \
          pa[i].x *= tt; pa[i].y *= tt; pa[i].z *= tt; pa[i].w *= tt;                  \
        }                                                                              \
      }                                                                                \
    }                                                                                  \
  }
#define LOADB(KC)                                                                      \
  {                                                                                    \
    _Pragma("unroll") for (int n = 0; n < 2; ++n) {                                    \
      const int ga = (((KC)*8 + wv * 2 + n) * 64 + lane) * 8;                          \
      pbh[n] = *(const short8*)(Whi + ga);                                             \
      pbl[n] = *(const short8*)(Wlo + ga);                                             \
    }                                                                                  \
  }

  LOADA(0) LOADB(0)

#pragma unroll
  for (int kc = 0; kc < 8; ++kc) {
    if (kc < 4) {
#pragma unroll
      for (int i = 0; i < 2; ++i) {
        *(ushort4*)(Ah + sdst[i]) = pmh[i];
        *(ushort4*)(Al + sdst[i]) = pml[i];
      }
    } else {
#pragma unroll
      for (int i = 0; i < 2; ++i) {
        ushort4 hv, lv;
        hv.x = f2b(pa[i].x); lv.x = f2b(pa[i].x - b2f(hv.x));
        hv.y = f2b(pa[i].y); lv.y = f2b(pa[i].y - b2f(hv.y));
        hv.z = f2b(pa[i].z); lv.z = f2b(pa[i].z - b2f(hv.z));
        hv.w = f2b(pa[i].w); lv.w = f2b(pa[i].w - b2f(hv.w));
        *(ushort4*)(Ah + sdst[i]) = hv;
        *(ushort4*)(Al + sdst[i]) = lv;
      }
    }
    short8 bh[2], bl[2];
    bh[0] = pbh[0]; bh[1] = pbh[1];
    bl[0] = pbl[0]; bl[1] = pbl[1];
    __syncthreads();
    short8 ah[4], al[4];
#pragma unroll
    for (int m = 0; m < 4; ++m) {
      ah[m] = *(const short8*)(Ah + (m * 64 + lane) * 8);
      al[m] = *(const short8*)(Al + (m * 64 + lane) * 8);
    }
    switch (kc) {  // prefetch overlaps MFMA below
      case 0: LOADA(1) LOADB(1) break;
      case 1: LOADA(2) LOADB(2) break;
      case 2: LOADA(3) LOADB(3) break;
      case 3: LOADA(4) LOADB(4) break;
      case 4: LOADA(5) LOADB(5) break;
      case 5: LOADA(6) LOADB(6) break;
      case 6: LOADA(7) LOADB(7) break;
      default: break;
    }
#pragma unroll
    for (int m = 0; m < 4; ++m)
#pragma unroll
      for (int n = 0; n < 2; ++n) {
        acc[m][n] = __builtin_amdgcn_mfma_f32_16x16x32_bf16(ah[m], bh[n], acc[m][n], 0, 0, 0);
        acc[m][n] = __builtin_amdgcn_mfma_f32_16x16x32_bf16(ah[m], bl[n], acc[m][n], 0, 0, 0);
        acc[m][n] = __builtin_amdgcn_mfma_f32_16x16x32_bf16(al[m], bh[n], acc[m][n], 0, 0, 0);
      }
    __syncthreads();
  }
#undef LOADA
#undef LOADB

  const int c0 = wv * 32 + li;
  const int c1 = wv * 32 + 16 + li;
  const float b0 = bias[c0], b1 = bias[c1];
  const float p0 = pw[c0], p1 = pw[c1];
  float sp[16];
#pragma unroll
  for (int m = 0; m < 4; ++m) {
#pragma unroll
    for (int i = 0; i < 4; ++i) {
      const int r = row0 + m * 16 + q * 4 + i;
      const float v0 = fmaxf(acc[m][0][i] + b0, 0.f);
      const float v1 = fmaxf(acc[m][1][i] + b1, 0.f);
      outp[(size_t)r * DD + c0] = v0;
      outp[(size_t)r * DD + c1] = v1;
      sp[m * 4 + i] = v0 * p0 + v1 * p1;
    }
  }
#pragma unroll
  for (int e = 0; e < 16; ++e) {
    sp[e] += __shfl_xor(sp[e], 1);
    sp[e] += __shfl_xor(sp[e], 2);
    sp[e] += __shfl_xor(sp[e], 4);
    sp[e] += __shfl_xor(sp[e], 8);
  }
  if (li == 0) {
#pragma unroll
    for (int e = 0; e < 16; ++e) s_sp[wv][(e >> 2) * 16 + q * 4 + (e & 3)] = sp[e];
  }
  __syncthreads();
  if (tid < GBM)
    sraw[row0 + tid] = s_sp[0][tid] + s_sp[1][tid] + s_sp[2][tid] + s_sp[3][tid];
}

// ---------------- topk + readout partials (R8, layers 0 and 1 only) ------------

__global__ __launch_bounds__(256) void pool_kernel(const float* __restrict__ h,
                                                   const float* __restrict__ sraw,
                                                   const float* __restrict__ pw,
                                                   const float2* __restrict__ tmP,
                                                   float2* __restrict__ tmN,
                                                   float* __restrict__ zp,
                                                   const int kk) {
  __shared__ float s_sc[NPER];
  __shared__ float s_t[128];
  __shared__ unsigned char s_sel[128];
  __shared__ int s_rk[256];
  __shared__ float4 red4[512];
  __shared__ float s_norm;
  const int b = blockIdx.x;
  const int g = b >> 2;
  const int q = b & 3;
  const int tid = threadIdx.x;
  const int lane = tid & 63;

  if (tid < 64) {
    const float v0 = pw[lane], v1 = pw[lane + 64];
    float p = v0 * v0 + v1 * v1;
#pragma unroll
    for (int o = 32; o > 0; o >>= 1) p += __shfl_down(p, o);
    if (lane == 0) s_norm = 1.f / (sqrtf(p) + 1e-16f);
  }
  __syncthreads();
  const float inv_norm = s_norm;
#pragma unroll
  for (int i = 0; i < 2; ++i) {
    const int n = tid + i * 256;
    const int node = g * NPER + n;
    s_sc[n] = (tmP[node].x != 0.f) ? sraw[node] * inv_norm : -INFINITY;
  }
  __syncthreads();

  {
    const int n = q * 128 + (tid & 127);
    const int jb = (tid >> 7) * 256;
    const float s = s_sc[n];
    int rank = 0;
    for (int j = jb; j < jb + 256; ++j) {
      const float sj = s_sc[j];
      rank += (sj > s || (sj == s && j < n)) ? 1 : 0;
    }
    s_rk[tid] = rank;
  }
  __syncthreads();
  if (tid < 128) {
    const int n = q * 128 + tid;
    const int rank = s_rk[tid] + s_rk[tid + 128];
    const int sel = (rank < kk) ? 1 : 0;
    const float s = s_sc[n];
    const float t = sel ? tanhf(s) : 0.f;
    tmN[g * NPER + n] = make_float2(sel ? 1.f : 0.f, t);
    s_sel[tid] = (unsigned char)sel;
    s_t[tid] = t;
  }
  __syncthreads();

  const int c = tid & 31;
  const int r = tid >> 5;
  float4 pmax = make_float4(-INFINITY, -INFINITY, -INFINITY, -INFINITY);
  float4 psum = make_float4(0.f, 0.f, 0.f, 0.f);
  const size_t nbase = (size_t)g * NPER + q * 128;
  const float4* h4 = (const float4*)h;
  for (int i = 0; i < 16; ++i) {
    const int nl = r + 8 * i;
    if (s_sel[nl]) {
      float4 v = h4[(nbase + nl) * 32 + c];
      const float t = s_t[nl];
      v.x *= t; v.y *= t; v.z *= t; v.w *= t;
      pmax.x = fmaxf(pmax.x, v.x);
      pmax.y = fmaxf(pmax.y, v.y);
      pmax.z = fmaxf(pmax.z, v.z);
      pmax.w = fmaxf(pmax.w, v.w);
      psum.x += v.x; psum.y += v.y; psum.z += v.z; psum.w += v.w;
    }
  }
  red4[r * 32 + c] = pmax;
  red4[256 + r * 32 + c] = psum;
  __syncthreads();
  if (tid < 32) {
    float4 m = red4[tid];
    float4 sm2 = red4[256 + tid];
#pragma unroll
    for (int rr = 1; rr < 8; ++rr) {
      const float4 a = red4[rr * 32 + tid];
      const float4 s3 = red4[256 + rr * 32 + tid];
      m.x = fmaxf(m.x, a.x); m.y = fmaxf(m.y, a.y);
      m.z = fmaxf(m.z, a.z); m.w = fmaxf(m.w, a.w);
      sm2.x += s3.x; sm2.y += s3.y; sm2.z += s3.z; sm2.w += s3.w;
    }
    *(float4*)(zp + (size_t)b * 256 + tid * 4) = m;
    *(float4*)(zp + (size_t)b * 256 + 128 + tid * 4) = sm2;
  }
}

// ---------------- head: pool-2 + readout-2 + zpart reduce + MLP ----------------
// one block per graph (pool computed ONCE per graph -- R12's 16x redundancy bug
// is what killed the folded version; this folding is redundancy-free).

__device__ __forceinline__ int rank_of(const float* s_sc, const float s, const int n) {
  int r = 0;
  for (int j = 0; j < NPER; j += 4) {
    const float4 sj = *(const float4*)(s_sc + j);
    r += (sj.x > s || (sj.x == s && (j + 0) < n)) ? 1 : 0;
    r += (sj.y > s || (sj.y == s && (j + 1) < n)) ? 1 : 0;
    r += (sj.z > s || (sj.z == s && (j + 2) < n)) ? 1 : 0;
    r += (sj.w > s || (sj.w == s && (j + 3) < n)) ? 1 : 0;
  }
  return r;
}

__global__ __launch_bounds__(256) void head_kernel(
    const float* __restrict__ h3, const float* __restrict__ s2buf,
    const float2* __restrict__ tm2, const float* __restrict__ pw2, const int kk,
    const float* __restrict__ zpart,
    const float* __restrict__ w1, const float* __restrict__ b1,
    const float* __restrict__ w2, const float* __restrict__ b2,
    const float* __restrict__ w3, const float* __restrict__ b3,
    float* __restrict__ out) {
  __shared__ float2 s_tm[NPER];
  __shared__ alignas(16) float scbuf[1024];
  __shared__ float z3m[128], z3s[128];
  __shared__ float z[256], sh1[128], sh2[64];
  __shared__ float s_norm;
  const int g = blockIdx.x;
  const int tid = threadIdx.x;
  const int lane = tid & 63;

  if (tid < 64) {
    const float v0 = pw2[lane], v1 = pw2[lane + 64];
    float p = v0 * v0 + v1 * v1;
#pragma unroll
    for (int o = 32; o > 0; o >>= 1) p += __shfl_down(p, o);
    if (lane == 0) s_norm = 1.f / (sqrtf(p) + 1e-16f);
  }
  __syncthreads();
  const float inv_norm = s_norm;
  const int node0 = g * NPER + tid;
  const int node1 = node0 + 256;
  const float sc0 = (tm2[node0].x != 0.f) ? s2buf[node0] * inv_norm : -INFINITY;
  const float sc1 = (tm2[node1].x != 0.f) ? s2buf[node1] * inv_norm : -INFINITY;
  scbuf[tid] = sc0;
  scbuf[tid + 256] = sc1;
  __syncthreads();
  const int r0 = rank_of(scbuf, sc0, tid);
  const int r1 = rank_of(scbuf, sc1, tid + 256);
  s_tm[tid] = (r0 < kk) ? make_float2(1.f, tanhf(sc0)) : make_float2(0.f, 0.f);
  s_tm[tid + 256] = (r1 < kk) ? make_float2(1.f, tanhf(sc1)) : make_float2(0.f, 0.f);
  __syncthreads();

  // readout of h3 (whole graph)
  {
    float4* red4 = (float4*)scbuf;
    const int c = tid & 31;
    const int rg = tid >> 5;
    float4 rmax = make_float4(-INFINITY, -INFINITY, -INFINITY, -INFINITY);
    float4 rsum = make_float4(0.f, 0.f, 0.f, 0.f);
    for (int i = 0; i < 64; ++i) {
      const int rloc = rg + 8 * i;
      const float2 mt = s_tm[rloc];
      float4 v = *(const float4*)(h3 + (size_t)(g * NPER + rloc) * DD + c * 4);
      v.x *= mt.y; v.y *= mt.y; v.z *= mt.y; v.w *= mt.y;
      rsum.x += v.x; rsum.y += v.y; rsum.z += v.z; rsum.w += v.w;
      if (mt.x != 0.f) {
        rmax.x = fmaxf(rmax.x, v.x);
        rmax.y = fmaxf(rmax.y, v.y);
        rmax.z = fmaxf(rmax.z, v.z);
        rmax.w = fmaxf(rmax.w, v.w);
      }
    }
    red4[rg * 32 + c] = rmax;
    __syncthreads();
    float4 zm = make_float4(0.f, 0.f, 0.f, 0.f);
    if (tid < 32) {
      zm = red4[tid];
#pragma unroll
      for (int rr = 1; rr < 8; ++rr) {
        const float4 a = red4[rr * 32 + tid];
        zm.x = fmaxf(zm.x, a.x); zm.y = fmaxf(zm.y, a.y);
        zm.z = fmaxf(zm.z, a.z); zm.w = fmaxf(zm.w, a.w);
      }
    }
    __syncthreads();
    red4[rg * 32 + c] = rsum;
    __syncthreads();
    if (tid < 32) {
      float4 zs = red4[tid];
#pragma unroll
      for (int rr = 1; rr < 8; ++rr) {
        const float4 a = red4[rr * 32 + tid];
        zs.x += a.x; zs.y += a.y; zs.z += a.z; zs.w += a.w;
      }
      *(float4*)(z3m + tid * 4) = zm;
      *(float4*)(z3s + tid * 4) = zs;
    }
  }
  __syncthreads();

  if (tid < 128) {
    // reduce 4 partials/graph for layers 0,1 (R8 zpart format)
    const float* zp0 = zpart + ((size_t)0 * 512 + g * 4) * 256;
    const float* zp1 = zpart + ((size_t)1 * 512 + g * 4) * 256;
    const float m0 = fmaxf(fmaxf(zp0[tid], zp0[256 + tid]), fmaxf(zp0[512 + tid], zp0[768 + tid]));
    const float s0 = zp0[128 + tid] + zp0[384 + tid] + zp0[640 + tid] + zp0[896 + tid];
    const float m1 = fmaxf(fmaxf(zp1[tid], zp1[256 + tid]), fmaxf(zp1[512 + tid], zp1[768 + tid]));
    const float s1 = zp1[128 + tid] + zp1[384 + tid] + zp1[640 + tid] + zp1[896 + tid];
    z[tid] = m0 + m1 + z3m[tid];
    z[128 + tid] = s0 * (1.f / 410.f) + s1 * (1.f / 328.f) + z3s[tid] * (1.f / 263.f);
  }
  __syncthreads();
  if (tid < 128) {
    float a = b1[tid];
    for (int k = 0; k < 256; ++k) a = fmaf(z[k], w1[tid * 256 + k], a);
    sh1[tid] = fmaxf(a, 0.f);
  }
  __syncthreads();
  if (tid < 64) {
    float a2 = b2[tid];
    for (int k = 0; k < 128; ++k) a2 = fmaf(sh1[k], w2[tid * 128 + k], a2);
    sh2[tid] = fmaxf(a2, 0.f);
  }
  __syncthreads();
  if (tid == 0) {
    float a3 = b3[0];
    for (int k = 0; k < 64; ++k) a3 = fmaf(sh2[k], w3[k], a3);
    out[g] = 1.f / (1.f + expf(-a3));
  }
}

// ---------------- launch ----------------

extern "C" void kernel_launch(void* const* d_in, const int* in_sizes, int n_in,
                              void* d_out, int out_size, void* d_ws, size_t ws_size,
                              hipStream_t stream) {
  (void)in_sizes; (void)n_in; (void)out_size; (void)ws_size;
  const float* x_in = (const float*)d_in[0];
  const int* ei = (const int*)d_in[1];
  const float* wl[3] = {(const float*)d_in[2], (const float*)d_in[6], (const float*)d_in[10]};
  const float* cbl[3] = {(const float*)d_in[3], (const float*)d_in[7], (const float*)d_in[11]};
  const float* wr[3] = {(const float*)d_in[4], (const float*)d_in[8], (const float*)d_in[12]};
  const float* pw[3] = {(const float*)d_in[5], (const float*)d_in[9], (const float*)d_in[13]};
  const float* l1w = (const float*)d_in[14];
  const float* l1b = (const float*)d_in[15];
  const float* l2w = (const float*)d_in[16];
  const float* l2b = (const float*)d_in[17];
  const float* l3w = (const float*)d_in[18];
  const float* l3b = (const float*)d_in[19];
  float* out = (float*)d_out;

  char* w = (char*)d_ws;
  int* counts = (int*)(w + 0 * (1 << 20));    // dead after scan
  int* off = (int*)(w + 1 * (1 << 20));
  int* cursor = (int*)(w + 2 * (1 << 20));    // dead after scatter
  float* sraw = (float*)(w + 2 * (1 << 20));  // reuses cursor (256KB)
  float2* tmA = (float2*)(w + 3 * (1 << 20));              // 512KB
  float2* tmB = (float2*)(w + 3 * (1 << 20) + (1 << 19));  // 512KB
  float* zpart = (float*)(w + 4 * (1 << 20));              // 1MB (2 layers x 512KB)
  unsigned short* Whi = (unsigned short*)(w + 5 * (1 << 20) + (1 << 19));      // 192KB
  unsigned short* Wlo = (unsigned short*)(w + 5 * (1 << 20) + 3 * (1 << 18));  // 192KB
  int* ssrc = (int*)(w + 6 * (1 << 20));                                 // 2MB
  unsigned short* mhi = (unsigned short*)(w + (size_t)8 * (1 << 20));    // 16MB
  unsigned short* mlo = (unsigned short*)(w + (size_t)24 * (1 << 20));   // 16MB
  float* hA = (float*)(w + (size_t)40 * (1 << 20));  // 32MB
  float* hB = (float*)(w + (size_t)72 * (1 << 20));  // 32MB (total 104MB)

  setup_kernel<<<384, 256, 0, stream>>>(counts, tmA, wl[0], wr[0], wl[1], wr[1], wl[2], wr[2],
                                        Whi, Wlo);
  hist_kernel<<<NED / 256, 256, 0, stream>>>(ei, counts);
  scan_kernel<<<1, 1024, 0, stream>>>(counts, off, cursor);
  scatter_kernel<<<NED / 256, 256, 0, stream>>>(ei, cursor, ssrc);

  const int ks[3] = {410, 328, 263};
  const float* xl = x_in;
  float* houts[3] = {hA, hB, hA};
  float2* tprev[3] = {tmA, tmB, tmA};
  float2* tnext[3] = {tmB, tmA, tmB};
  for (int l = 0; l < 3; ++l) {
    float* hout = houts[l];
    if (l == 0) {
      agg_kernel_t<0><<<4096, 256, 0, stream>>>(xl, tprev[l], off, ssrc, mhi, mlo);
      gemm_kernel_t<0><<<NND / GBM, 256, 0, stream>>>(mhi, mlo, xl, tprev[l],
                                                      Whi + (size_t)l * 32768,
                                                      Wlo + (size_t)l * 32768, cbl[l], pw[l],
                                                      hout, sraw);
    } else {
      agg_kernel_t<1><<<4096, 256, 0, stream>>>(xl, tprev[l], off, ssrc, mhi, mlo);
      gemm_kernel_t<1><<<NND / GBM, 256, 0, stream>>>(mhi, mlo, xl, tprev[l],
                                                      Whi + (size_t)l * 32768,
                                                      Wlo + (size_t)l * 32768, cbl[l], pw[l],
                                                      hout, sraw);
    }
    if (l < 2)
      pool_kernel<<<NGR * 4, 256, 0, stream>>>(hout, sraw, pw[l], tprev[l], tnext[l],
                                               zpart + (size_t)l * 512 * 256, ks[l]);
    xl = hout;
  }
  // head: pool-2 (k=263, gated by tmA = pool-1 output) + readout + MLP
  head_kernel<<<NGR, 256, 0, stream>>>(hA, sraw, tmA, pw[2], 263, zpart, l1w, l1b, l2w, l2b,
                                       l3w, l3b, out);
}